// Round 5
// baseline (248.111 us; speedup 1.0000x reference)
//
#include <hip/hip_runtime.h>
#include <hip/hip_bf16.h>

#define IN_DIM 98304

typedef short bh8 __attribute__((ext_vector_type(8)));
typedef float f32x4 __attribute__((ext_vector_type(4)));
typedef unsigned short u16x8 __attribute__((ext_vector_type(8)));

__device__ __forceinline__ unsigned short f2bf(float f) {
  __hip_bfloat16 h = __float2bfloat16(f);
  return __builtin_bit_cast(unsigned short, h);
}

__device__ __forceinline__ void bfly(float2& a, float2& b, float wr, float wi) {
  float tr = wr * b.x - wi * b.y;
  float ti = wr * b.y + wi * b.x;
  b.x = a.x - tr; b.y = a.y - ti;
  a.x += tr; a.y += ti;
}

__device__ __forceinline__ float2 cmul(float2 a, float2 w) {
  return make_float2(a.x * w.x - a.y * w.y, a.x * w.y + a.y * w.x);
}

// 16-point FFT, input bit-reversed in v[], output natural order.
__device__ __forceinline__ void fft16(float2* v) {
  const float C8 = 0.70710678118654752f;
  const float C161 = 0.92387953251128674f, S161 = 0.38268343236508977f;
#pragma unroll
  for (int i = 0; i < 16; i += 2) bfly(v[i], v[i + 1], 1.f, 0.f);
#pragma unroll
  for (int i = 0; i < 16; i += 4) {
    bfly(v[i], v[i + 2], 1.f, 0.f);
    bfly(v[i + 1], v[i + 3], 0.f, -1.f);
  }
  {
    const float w8r[4] = {1.f, C8, 0.f, -C8};
    const float w8i[4] = {0.f, -C8, -1.f, -C8};
#pragma unroll
    for (int i = 0; i < 16; i += 8) {
#pragma unroll
      for (int j = 0; j < 4; ++j) bfly(v[i + j], v[i + j + 4], w8r[j], w8i[j]);
    }
  }
  {
    const float w16r[8] = {1.f, C161, C8, S161, 0.f, -S161, -C8, -C161};
    const float w16i[8] = {0.f, -S161, -C8, -C161, -1.f, -C161, -C8, -S161};
#pragma unroll
    for (int j = 0; j < 8; ++j) bfly(v[j], v[j + 8], w16r[j], w16i[j]);
  }
}

// 8-point FFT, input bit-reversed in v[], output natural order.
__device__ __forceinline__ void fft8(float2* v) {
  const float C8 = 0.70710678118654752f;
#pragma unroll
  for (int i = 0; i < 8; i += 2) bfly(v[i], v[i + 1], 1.f, 0.f);
#pragma unroll
  for (int i = 0; i < 8; i += 4) {
    bfly(v[i], v[i + 2], 1.f, 0.f);
    bfly(v[i + 1], v[i + 3], 0.f, -1.f);
  }
  bfly(v[0], v[4], 1.f, 0.f);
  bfly(v[1], v[5], C8, -C8);
  bfly(v[2], v[6], 0.f, -1.f);
  bfly(v[3], v[7], -C8, -C8);
}

// swizzled LDS index (float2 units)
__device__ __forceinline__ int IDX(int r, int cc) {
  return (r << 7) + (cc ^ ((r & 7) << 1));
}

// ---------------------------------------------------------------------------
// Kernel 1: 128x128 FFT2 + fftshift + amp/phase -> bf16 feats.
// 1024 threads (4 waves/SIMD) -- each slot handled exactly once per stage.
// ---------------------------------------------------------------------------
__global__ __launch_bounds__(1024) void fft_feats_kernel(
    const float* __restrict__ img, unsigned short* __restrict__ feats) {
  __shared__ float2 sm[16384];
  __shared__ float2 tw[128];
  const int tid = threadIdx.x;
  const int c = blockIdx.x, b = blockIdx.y;
  const float* src = img + ((size_t)(b * 3 + c) << 14);

  static const int BR4[16] = {0, 8, 4, 12, 2, 10, 6, 14, 1, 9, 5, 13, 3, 11, 7, 15};
  static const int BR3[8] = {0, 4, 2, 6, 1, 5, 3, 7};

  if (tid < 128) {
    float sv, cv;
    sincosf(-6.28318530717958647692f * (float)tid / 128.0f, &sv, &cv);
    tw[tid] = make_float2(cv, sv);
  }
#pragma unroll
  for (int i4 = tid; i4 < 4096; i4 += 1024) {
    float4 x = *reinterpret_cast<const float4*>(src + (i4 << 2));
    int r = i4 >> 5, cc = (i4 << 2) & 127;
    *reinterpret_cast<float4*>(&sm[IDX(r, cc)]) = make_float4(x.x, 0.f, x.y, 0.f);
    *reinterpret_cast<float4*>(&sm[IDX(r, cc + 2)]) = make_float4(x.z, 0.f, x.w, 0.f);
  }
  __syncthreads();

  // ---- row pass, stage 1: slot (r, n2)
  {
    int r = tid >> 3, n2 = tid & 7;
    float2 v[16];
#pragma unroll
    for (int j = 0; j < 16; ++j) v[j] = sm[IDX(r, (BR4[j] << 3) + n2)];
    fft16(v);
#pragma unroll
    for (int k1 = 1; k1 < 16; ++k1) v[k1] = cmul(v[k1], tw[n2 * k1]);
#pragma unroll
    for (int k1 = 0; k1 < 16; ++k1) sm[IDX(r, (k1 << 3) + n2)] = v[k1];
  }
  __syncthreads();

  // ---- row pass, stage 2: slot (r, t8)
  {
    int r = tid >> 3, t8 = tid & 7;
    float2 u0[8], u1[8];
#pragma unroll
    for (int j = 0; j < 8; ++j) {
      u0[j] = sm[IDX(r, (t8 << 3) + BR3[j])];
      u1[j] = sm[IDX(r, ((t8 + 8) << 3) + BR3[j])];
    }
    __syncthreads();  // all reads before any writes
    fft8(u0);
    fft8(u1);
#pragma unroll
    for (int k2 = 0; k2 < 8; ++k2) {
      sm[IDX(r, t8 + (k2 << 4))] = u0[k2];
      sm[IDX(r, t8 + 8 + (k2 << 4))] = u1[k2];
    }
  }
  __syncthreads();

  // ---- col pass, stage 1: slot (col, n2); touches only rows == n2 (mod 8)
  {
    int col = tid & 127, n2 = tid >> 7;
    float2 v[16];
#pragma unroll
    for (int j = 0; j < 16; ++j) v[j] = sm[IDX((BR4[j] << 3) + n2, col)];
    fft16(v);
#pragma unroll
    for (int k1 = 1; k1 < 16; ++k1) v[k1] = cmul(v[k1], tw[n2 * k1]);
#pragma unroll
    for (int k1 = 0; k1 < 16; ++k1) sm[IDX((k1 << 3) + n2, col)] = v[k1];
  }
  __syncthreads();

  // ---- col pass, stage 2 + fftshift + amp/phase + global write
  unsigned short* dst = feats + (size_t)b * IN_DIM + c * 32768;
  {
    int col = tid & 127, t8 = tid >> 7;
    float2 u0[8], u1[8];
#pragma unroll
    for (int j = 0; j < 8; ++j) {
      u0[j] = sm[IDX((t8 << 3) + BR3[j], col)];
      u1[j] = sm[IDX(((t8 + 8) << 3) + BR3[j], col)];
    }
    fft8(u0);
    fft8(u1);
    int ow = col ^ 64;
#pragma unroll
    for (int k2 = 0; k2 < 8; ++k2) {
      int oh0 = (t8 + (k2 << 4)) ^ 64;
      int oh1 = (t8 + 8 + (k2 << 4)) ^ 64;
      float a0 = sqrtf(u0[k2].x * u0[k2].x + u0[k2].y * u0[k2].y);
      float p0 = atan2f(u0[k2].y, u0[k2].x);
      float a1 = sqrtf(u1[k2].x * u1[k2].x + u1[k2].y * u1[k2].y);
      float p1 = atan2f(u1[k2].y, u1[k2].x);
      dst[(oh0 << 7) + ow] = f2bf(a0);
      dst[16384 + (oh0 << 7) + ow] = f2bf(p0);
      dst[(oh1 << 7) + ow] = f2bf(a1);
      dst[16384 + (oh1 << 7) + ow] = f2bf(p1);
    }
  }
}

// ---------------------------------------------------------------------------
// Kernel 2: layer-1 GEMM, split-K. BARRIER-FREE, ZERO-LDS.
// Each wave owns a 64x64 output tile: A-frags (bf16) and B-frags
// (fp32 -> cvt to bf16) loaded straight from global to registers.
// Per instruction the wave covers 16 rows x 64B contiguous -> coalesced.
// No __syncthreads anywhere; waves free-run, TLP hides HBM latency.
// ---------------------------------------------------------------------------
__global__ __launch_bounds__(256, 2) void gemm1_kernel(
    const unsigned short* __restrict__ feats, const float* __restrict__ W1,
    float* __restrict__ partial, int S, int iters) {
  const int tid = threadIdx.x;
  const int wv = tid >> 6, lane = tid & 63;

  // XCD-aware decode: blocks with the same ks land on the same XCD.
  const int f = blockIdx.x;
  const int kpx = S >> 3;
  const int xcd = f & 7, j = f >> 3;
  const int ks = kpx * xcd + (j % kpx);
  const int nt = j / kpx;
  const int n0 = nt * 64;
  const int m0 = wv * 64;  // wave owns rows m0..m0+63
  const size_t k0 = (size_t)ks * ((size_t)iters * 32);

  const int rm = lane & 15, ko = (lane >> 4) * 8;

  const unsigned short* ap[4];
  const float* bp[4];
#pragma unroll
  for (int i = 0; i < 4; ++i)
    ap[i] = feats + (size_t)(m0 + i * 16 + rm) * IN_DIM + k0 + ko;
#pragma unroll
  for (int i = 0; i < 4; ++i)
    bp[i] = W1 + (size_t)(n0 + i * 16 + rm) * IN_DIM + k0 + ko;

  f32x4 acc[4][4];
#pragma unroll
  for (int i = 0; i < 4; ++i)
#pragma unroll
    for (int jj = 0; jj < 4; ++jj) acc[i][jj] = (f32x4){0.f, 0.f, 0.f, 0.f};

#define LOADT(AS, BS, kk)                                                     \
  _Pragma("unroll") for (int i = 0; i < 4; ++i)                               \
      AS[i] = *reinterpret_cast<const u16x8*>(ap[i] + (size_t)(kk) * 32);     \
  _Pragma("unroll") for (int i = 0; i < 4; ++i) {                             \
    const float* p_ = bp[i] + (size_t)(kk) * 32;                              \
    BS[i][0] = *reinterpret_cast<const float4*>(p_);                          \
    BS[i][1] = *reinterpret_cast<const float4*>(p_ + 4);                      \
  }

#define COMP(AS, BS)                                                          \
  {                                                                           \
    bh8 bb[4];                                                                \
    _Pragma("unroll") for (int i = 0; i < 4; ++i) {                           \
      bb[i][0] = (short)f2bf(BS[i][0].x); bb[i][1] = (short)f2bf(BS[i][0].y); \
      bb[i][2] = (short)f2bf(BS[i][0].z); bb[i][3] = (short)f2bf(BS[i][0].w); \
      bb[i][4] = (short)f2bf(BS[i][1].x); bb[i][5] = (short)f2bf(BS[i][1].y); \
      bb[i][6] = (short)f2bf(BS[i][1].z); bb[i][7] = (short)f2bf(BS[i][1].w); \
    }                                                                         \
    _Pragma("unroll") for (int i = 0; i < 4; ++i)                             \
        _Pragma("unroll") for (int jj = 0; jj < 4; ++jj)                      \
            acc[i][jj] = __builtin_amdgcn_mfma_f32_16x16x32_bf16(             \
                (bh8)AS[i], bb[jj], acc[i][jj], 0, 0, 0);                     \
  }

  u16x8 a0[4], a1[4];
  float4 b0[4][2], b1[4][2];

  LOADT(a0, b0, 0);
  for (int k = 0; k < iters; k += 2) {
    if (k + 1 < iters) { LOADT(a1, b1, k + 1); }
    COMP(a0, b0);
    if (k + 2 < iters) { LOADT(a0, b0, k + 2); }
    COMP(a1, b1);
  }
#undef LOADT
#undef COMP

  // epilogue: C/D layout col=lane&15, row=(lane>>4)*4+reg (m89-verified)
  const int rg = lane >> 4;
  float* pbase = partial + ((size_t)ks << 17);
#pragma unroll
  for (int i = 0; i < 4; ++i) {
#pragma unroll
    for (int jj = 0; jj < 4; ++jj) {
      int n = n0 + jj * 16 + rm;
#pragma unroll
      for (int r = 0; r < 4; ++r) {
        int m = m0 + i * 16 + rg * 4 + r;
        pbase[((size_t)m << 9) + n] = acc[i][jj][r];
      }
    }
  }
}

// ---------------------------------------------------------------------------
// Kernel 3: reduce split-K partials + bias + ReLU -> x1 [256][512] fp32
// ---------------------------------------------------------------------------
__global__ __launch_bounds__(256) void reduce1_kernel(
    const float* __restrict__ partial, const float* __restrict__ b1,
    float* __restrict__ x1, int S) {
  int i = blockIdx.x * 256 + threadIdx.x;  // 0..131071
  float s = b1[i & 511];
  for (int p = 0; p < S; ++p) s += partial[((size_t)p << 17) + i];
  x1[i] = fmaxf(s, 0.0f);
}

// ---------------------------------------------------------------------------
// Kernel 4: x2 = relu(x1 @ W2^T + b2)
// ---------------------------------------------------------------------------
__global__ __launch_bounds__(256) void fc2_kernel(
    const float* __restrict__ x1, const float* __restrict__ W2,
    const float* __restrict__ b2, float* __restrict__ x2) {
  __shared__ float xs[512];
  int b = blockIdx.x, n = threadIdx.x;
  xs[n] = x1[b * 512 + n];
  xs[n + 256] = x1[b * 512 + 256 + n];
  __syncthreads();
  float acc = b2[n];
  const float* wr = W2 + (size_t)n * 512;
#pragma unroll 4
  for (int k = 0; k < 512; k += 4) {
    float4 w = *reinterpret_cast<const float4*>(wr + k);
    acc += xs[k] * w.x + xs[k + 1] * w.y + xs[k + 2] * w.z + xs[k + 3] * w.w;
  }
  x2[b * 256 + n] = fmaxf(acc, 0.0f);
}

// ---------------------------------------------------------------------------
// Kernel 5: out = x2 @ W3^T + b3
// ---------------------------------------------------------------------------
__global__ __launch_bounds__(128) void fc3_kernel(
    const float* __restrict__ x2, const float* __restrict__ W3,
    const float* __restrict__ b3, float* __restrict__ out) {
  __shared__ float xs[256];
  int b = blockIdx.x, n = threadIdx.x;
  xs[n] = x2[b * 256 + n];
  xs[n + 128] = x2[b * 256 + 128 + n];
  __syncthreads();
  float acc = b3[n];
  const float* wr = W3 + (size_t)n * 256;
#pragma unroll 4
  for (int k = 0; k < 256; k += 4) {
    float4 w = *reinterpret_cast<const float4*>(wr + k);
    acc += xs[k] * w.x + xs[k + 1] * w.y + xs[k + 2] * w.z + xs[k + 3] * w.w;
  }
  out[b * 128 + n] = acc;
}

extern "C" void kernel_launch(void* const* d_in, const int* in_sizes, int n_in,
                              void* d_out, int out_size, void* d_ws, size_t ws_size,
                              hipStream_t stream) {
  const float* img = (const float*)d_in[0];
  const float* W1 = (const float*)d_in[1];
  const float* b1 = (const float*)d_in[2];
  const float* W2 = (const float*)d_in[3];
  const float* b2 = (const float*)d_in[4];
  const float* W3 = (const float*)d_in[5];
  const float* b3 = (const float*)d_in[6];
  float* out = (float*)d_out;
  char* ws = (char*)d_ws;

  const size_t FEATS_B = 50331648ull;  // bf16 [256][98304]
  const size_t TAIL_B = 524288ull + 262144ull;
  // split-K S: prefer 64 (512 blocks = 2/CU exactly), fallback 32
  int S = (ws_size >= FEATS_B + 64ull * 524288 + TAIL_B) ? 64 : 32;
  const int iters = IN_DIM / S / 32;  // 48 / 96 (even)

  unsigned short* feats = (unsigned short*)ws;
  float* partial = (float*)(ws + FEATS_B);
  float* x1 = partial + (size_t)S * 131072;
  float* x2 = x1 + 131072;

  hipLaunchKernelGGL(fft_feats_kernel, dim3(3, 256), dim3(1024), 0, stream, img, feats);
  hipLaunchKernelGGL(gemm1_kernel, dim3(8 * S), dim3(256), 0, stream,
                     feats, W1, partial, S, iters);
  hipLaunchKernelGGL(reduce1_kernel, dim3(512), dim3(256), 0, stream, partial, b1, x1, S);
  hipLaunchKernelGGL(fc2_kernel, dim3(256), dim3(256), 0, stream, x1, W2, b2, x2);
  hipLaunchKernelGGL(fc3_kernel, dim3(256), dim3(128), 0, stream, x2, W3, b3, out);
}

// Round 6
// 202.624 us; speedup vs baseline: 1.2245x; 1.2245x over previous
//
#include <hip/hip_runtime.h>
#include <hip/hip_bf16.h>

#define IN_DIM 98304

typedef short bh8 __attribute__((ext_vector_type(8)));
typedef float f32x4 __attribute__((ext_vector_type(4)));
typedef unsigned short u16x8 __attribute__((ext_vector_type(8)));

__device__ __forceinline__ unsigned short f2bf(float f) {
  __hip_bfloat16 h = __float2bfloat16(f);
  return __builtin_bit_cast(unsigned short, h);
}

__device__ __forceinline__ void gload_lds16(const void* g, void* l) {
  __builtin_amdgcn_global_load_lds(
      (const __attribute__((address_space(1))) void*)g,
      (__attribute__((address_space(3))) void*)l, 16, 0, 0);
}

__device__ __forceinline__ void bfly(float2& a, float2& b, float wr, float wi) {
  float tr = wr * b.x - wi * b.y;
  float ti = wr * b.y + wi * b.x;
  b.x = a.x - tr; b.y = a.y - ti;
  a.x += tr; a.y += ti;
}

__device__ __forceinline__ float2 cmul(float2 a, float2 w) {
  return make_float2(a.x * w.x - a.y * w.y, a.x * w.y + a.y * w.x);
}

// 16-point FFT, input bit-reversed in v[], output natural order.
__device__ __forceinline__ void fft16(float2* v) {
  const float C8 = 0.70710678118654752f;
  const float C161 = 0.92387953251128674f, S161 = 0.38268343236508977f;
#pragma unroll
  for (int i = 0; i < 16; i += 2) bfly(v[i], v[i + 1], 1.f, 0.f);
#pragma unroll
  for (int i = 0; i < 16; i += 4) {
    bfly(v[i], v[i + 2], 1.f, 0.f);
    bfly(v[i + 1], v[i + 3], 0.f, -1.f);
  }
  {
    const float w8r[4] = {1.f, C8, 0.f, -C8};
    const float w8i[4] = {0.f, -C8, -1.f, -C8};
#pragma unroll
    for (int i = 0; i < 16; i += 8) {
#pragma unroll
      for (int j = 0; j < 4; ++j) bfly(v[i + j], v[i + j + 4], w8r[j], w8i[j]);
    }
  }
  {
    const float w16r[8] = {1.f, C161, C8, S161, 0.f, -S161, -C8, -C161};
    const float w16i[8] = {0.f, -S161, -C8, -C161, -1.f, -C161, -C8, -S161};
#pragma unroll
    for (int j = 0; j < 8; ++j) bfly(v[j], v[j + 8], w16r[j], w16i[j]);
  }
}

// 8-point FFT, input bit-reversed in v[], output natural order.
__device__ __forceinline__ void fft8(float2* v) {
  const float C8 = 0.70710678118654752f;
#pragma unroll
  for (int i = 0; i < 8; i += 2) bfly(v[i], v[i + 1], 1.f, 0.f);
#pragma unroll
  for (int i = 0; i < 8; i += 4) {
    bfly(v[i], v[i + 2], 1.f, 0.f);
    bfly(v[i + 1], v[i + 3], 0.f, -1.f);
  }
  bfly(v[0], v[4], 1.f, 0.f);
  bfly(v[1], v[5], C8, -C8);
  bfly(v[2], v[6], 0.f, -1.f);
  bfly(v[3], v[7], -C8, -C8);
}

// swizzled LDS index (float2 units)
__device__ __forceinline__ int IDX(int r, int cc) {
  return (r << 7) + (cc ^ ((r & 7) << 1));
}

// ---------------------------------------------------------------------------
// Kernel 1: 128x128 FFT2 + fftshift + amp/phase -> bf16 feats. 1024 threads.
// ---------------------------------------------------------------------------
__global__ __launch_bounds__(1024) void fft_feats_kernel(
    const float* __restrict__ img, unsigned short* __restrict__ feats) {
  __shared__ float2 sm[16384];
  __shared__ float2 tw[128];
  const int tid = threadIdx.x;
  const int c = blockIdx.x, b = blockIdx.y;
  const float* src = img + ((size_t)(b * 3 + c) << 14);

  static const int BR4[16] = {0, 8, 4, 12, 2, 10, 6, 14, 1, 9, 5, 13, 3, 11, 7, 15};
  static const int BR3[8] = {0, 4, 2, 6, 1, 5, 3, 7};

  if (tid < 128) {
    float sv, cv;
    sincosf(-6.28318530717958647692f * (float)tid / 128.0f, &sv, &cv);
    tw[tid] = make_float2(cv, sv);
  }
#pragma unroll
  for (int i4 = tid; i4 < 4096; i4 += 1024) {
    float4 x = *reinterpret_cast<const float4*>(src + (i4 << 2));
    int r = i4 >> 5, cc = (i4 << 2) & 127;
    *reinterpret_cast<float4*>(&sm[IDX(r, cc)]) = make_float4(x.x, 0.f, x.y, 0.f);
    *reinterpret_cast<float4*>(&sm[IDX(r, cc + 2)]) = make_float4(x.z, 0.f, x.w, 0.f);
  }
  __syncthreads();

  // ---- row pass, stage 1: slot (r, n2)
  {
    int r = tid >> 3, n2 = tid & 7;
    float2 v[16];
#pragma unroll
    for (int j = 0; j < 16; ++j) v[j] = sm[IDX(r, (BR4[j] << 3) + n2)];
    fft16(v);
#pragma unroll
    for (int k1 = 1; k1 < 16; ++k1) v[k1] = cmul(v[k1], tw[n2 * k1]);
#pragma unroll
    for (int k1 = 0; k1 < 16; ++k1) sm[IDX(r, (k1 << 3) + n2)] = v[k1];
  }
  __syncthreads();

  // ---- row pass, stage 2: slot (r, t8)
  {
    int r = tid >> 3, t8 = tid & 7;
    float2 u0[8], u1[8];
#pragma unroll
    for (int j = 0; j < 8; ++j) {
      u0[j] = sm[IDX(r, (t8 << 3) + BR3[j])];
      u1[j] = sm[IDX(r, ((t8 + 8) << 3) + BR3[j])];
    }
    __syncthreads();  // all reads before any writes
    fft8(u0);
    fft8(u1);
#pragma unroll
    for (int k2 = 0; k2 < 8; ++k2) {
      sm[IDX(r, t8 + (k2 << 4))] = u0[k2];
      sm[IDX(r, t8 + 8 + (k2 << 4))] = u1[k2];
    }
  }
  __syncthreads();

  // ---- col pass, stage 1: slot (col, n2)
  {
    int col = tid & 127, n2 = tid >> 7;
    float2 v[16];
#pragma unroll
    for (int j = 0; j < 16; ++j) v[j] = sm[IDX((BR4[j] << 3) + n2, col)];
    fft16(v);
#pragma unroll
    for (int k1 = 1; k1 < 16; ++k1) v[k1] = cmul(v[k1], tw[n2 * k1]);
#pragma unroll
    for (int k1 = 0; k1 < 16; ++k1) sm[IDX((k1 << 3) + n2, col)] = v[k1];
  }
  __syncthreads();

  // ---- col pass, stage 2 + fftshift + amp/phase + global write
  unsigned short* dst = feats + (size_t)b * IN_DIM + c * 32768;
  {
    int col = tid & 127, t8 = tid >> 7;
    float2 u0[8], u1[8];
#pragma unroll
    for (int j = 0; j < 8; ++j) {
      u0[j] = sm[IDX((t8 << 3) + BR3[j], col)];
      u1[j] = sm[IDX(((t8 + 8) << 3) + BR3[j], col)];
    }
    fft8(u0);
    fft8(u1);
    int ow = col ^ 64;
#pragma unroll
    for (int k2 = 0; k2 < 8; ++k2) {
      int oh0 = (t8 + (k2 << 4)) ^ 64;
      int oh1 = (t8 + 8 + (k2 << 4)) ^ 64;
      float a0 = sqrtf(u0[k2].x * u0[k2].x + u0[k2].y * u0[k2].y);
      float p0 = atan2f(u0[k2].y, u0[k2].x);
      float a1 = sqrtf(u1[k2].x * u1[k2].x + u1[k2].y * u1[k2].y);
      float p1 = atan2f(u1[k2].y, u1[k2].x);
      dst[(oh0 << 7) + ow] = f2bf(a0);
      dst[16384 + (oh0 << 7) + ow] = f2bf(p0);
      dst[(oh1 << 7) + ow] = f2bf(a1);
      dst[16384 + (oh1 << 7) + ow] = f2bf(p1);
    }
  }
}

// ---------------------------------------------------------------------------
// Kernel 2: layer-1 GEMM, split-K + split-M. ALL staging via global_load_lds,
// counted vmcnt(4) (never 0 mid-loop), 2 barriers/iter, no reg round-trips.
// MT=128, NT=64, BK=32. grid 16*S blocks = 4/CU at S=64. LDS 32KB/block.
// A: bf16 linear [128][32]. B: fp32 [64][32] with XOR-16B-slot swizzle
// (inverse-swizzled GLOBAL source + swizzled ds_read: rule both-sides).
// B fp32 -> bf16 conversion happens AFTER ds_read, in registers (no
// global->reg dataflow stall inside the MFMA cluster).
// ---------------------------------------------------------------------------
__global__ __launch_bounds__(256, 4) void gemm1_kernel(
    const unsigned short* __restrict__ feats, const float* __restrict__ W1,
    float* __restrict__ partial, int S, int iters) {
  __shared__ __align__(16) unsigned short Asm[2][128 * 32];  // 2 x 8 KB bf16
  __shared__ __align__(16) float Bsm[2][64 * 32];            // 2 x 8 KB fp32
  const int tid = threadIdx.x;
  const int wv = tid >> 6, lane = tid & 63;

  // XCD-aware decode: the 16 blocks sharing a ks land on one XCD (L2 reuse
  // of the A k-chunk and B k-chunk).
  const int f = blockIdx.x;
  const int kpx = S >> 3;            // ks values per XCD
  const int xcd = f & 7, g = f >> 3;
  const int ks = xcd * kpx + (g % kpx);
  const int t = g / kpx;             // 0..15
  const int mt = t & 1, nt = t >> 1;
  const int m0 = mt * 128, n0 = nt * 64;
  const size_t k0 = (size_t)ks * ((size_t)iters * 32);

  // A staging: chunk s (1KB) covers rows s*16..+15; lane -> row s*16+(l>>2),
  // bf16 k-offset (l&3)*8. LDS linear.
  const int al_row = lane >> 2;
  const int al_k = (lane & 3) * 8;
  // B staging: chunk s covers rows s*8..+7; lane -> row s*8+(l>>3).
  // Local row within chunk == (l>>3) == row&7. Inverse swizzle on SOURCE:
  // lane's 16B slot (l&7) receives global float4 index (l&7)^(l>>3).
  const int bl_row = lane >> 3;
  const int bl_f = ((lane & 7) ^ (lane >> 3)) * 4;  // float offset

  f32x4 acc[2][4];
#pragma unroll
  for (int i = 0; i < 2; ++i)
#pragma unroll
    for (int jj = 0; jj < 4; ++jj) acc[i][jj] = (f32x4){0.f, 0.f, 0.f, 0.f};

  auto stage = [&](int buf, int it) {
    const size_t kb = k0 + (size_t)it * 32;
#pragma unroll
    for (int tl = 0; tl < 2; ++tl) {
      const int s = wv * 2 + tl;  // 0..7
      const unsigned short* ga =
          feats + (size_t)(m0 + s * 16 + al_row) * IN_DIM + kb + al_k;
      gload_lds16(ga, (char*)&Asm[buf][0] + s * 1024);
      const float* gb = W1 + (size_t)(n0 + s * 8 + bl_row) * IN_DIM + kb + bl_f;
      gload_lds16(gb, (char*)&Bsm[buf][0] + s * 1024);
    }
  };

  stage(0, 0);
  stage(1, 1);

  const int rm = lane & 15, hi = lane >> 4;

  for (int k = 0; k < iters; ++k) {
    const int buf = k & 1;
    if (k + 1 < iters) {
      asm volatile("s_waitcnt vmcnt(4)" ::: "memory");
    } else {
      asm volatile("s_waitcnt vmcnt(0)" ::: "memory");
    }
    __builtin_amdgcn_sched_barrier(0);
    __builtin_amdgcn_s_barrier();
    __builtin_amdgcn_sched_barrier(0);

    bh8 afr[2];
    f32x4 braw[4][2];
#pragma unroll
    for (int i = 0; i < 2; ++i)
      afr[i] = *reinterpret_cast<const bh8*>(
          &Asm[buf][(wv * 32 + i * 16 + rm) * 32 + hi * 8]);
#pragma unroll
    for (int jj = 0; jj < 4; ++jj) {
      const int r = jj * 16 + rm;
      const int rb = r * 32;
      braw[jj][0] = *reinterpret_cast<const f32x4*>(
          &Bsm[buf][rb + (((hi * 2 + 0) ^ (r & 7)) * 4)]);
      braw[jj][1] = *reinterpret_cast<const f32x4*>(
          &Bsm[buf][rb + (((hi * 2 + 1) ^ (r & 7)) * 4)]);
    }
    asm volatile("s_waitcnt lgkmcnt(0)" ::: "memory");
    __builtin_amdgcn_sched_barrier(0);
    __builtin_amdgcn_s_barrier();
    __builtin_amdgcn_sched_barrier(0);

    if (k + 2 < iters) stage(buf, k + 2);  // loads fly over the MFMA cluster

    bh8 bfr[4];
#pragma unroll
    for (int jj = 0; jj < 4; ++jj) {
#pragma unroll
      for (int p = 0; p < 4; ++p) {
        bfr[jj][p] = (short)f2bf(braw[jj][0][p]);
        bfr[jj][4 + p] = (short)f2bf(braw[jj][1][p]);
      }
    }
#pragma unroll
    for (int i = 0; i < 2; ++i)
#pragma unroll
      for (int jj = 0; jj < 4; ++jj)
        acc[i][jj] = __builtin_amdgcn_mfma_f32_16x16x32_bf16(
            afr[i], bfr[jj], acc[i][jj], 0, 0, 0);
  }

  // epilogue: C/D layout col=lane&15, row=(lane>>4)*4+reg (m89-verified)
  const int rg = lane >> 4;
  float* pbase = partial + ((size_t)ks << 17);
#pragma unroll
  for (int i = 0; i < 2; ++i) {
#pragma unroll
    for (int jj = 0; jj < 4; ++jj) {
      const int n = n0 + jj * 16 + rm;
#pragma unroll
      for (int r = 0; r < 4; ++r) {
        const int m = m0 + wv * 32 + i * 16 + rg * 4 + r;
        pbase[((size_t)m << 9) + n] = acc[i][jj][r];
      }
    }
  }
}

// ---------------------------------------------------------------------------
// Kernel 3: reduce split-K partials + bias + ReLU -> x1 [256][512] fp32
// ---------------------------------------------------------------------------
__global__ __launch_bounds__(256) void reduce1_kernel(
    const float* __restrict__ partial, const float* __restrict__ b1,
    float* __restrict__ x1, int S) {
  int i = blockIdx.x * 256 + threadIdx.x;  // 0..131071
  float s = b1[i & 511];
  for (int p = 0; p < S; ++p) s += partial[((size_t)p << 17) + i];
  x1[i] = fmaxf(s, 0.0f);
}

// ---------------------------------------------------------------------------
// Kernel 4: x2 = relu(x1 @ W2^T + b2)
// ---------------------------------------------------------------------------
__global__ __launch_bounds__(256) void fc2_kernel(
    const float* __restrict__ x1, const float* __restrict__ W2,
    const float* __restrict__ b2, float* __restrict__ x2) {
  __shared__ float xs[512];
  int b = blockIdx.x, n = threadIdx.x;
  xs[n] = x1[b * 512 + n];
  xs[n + 256] = x1[b * 512 + 256 + n];
  __syncthreads();
  float acc = b2[n];
  const float* wr = W2 + (size_t)n * 512;
#pragma unroll 4
  for (int k = 0; k < 512; k += 4) {
    float4 w = *reinterpret_cast<const float4*>(wr + k);
    acc += xs[k] * w.x + xs[k + 1] * w.y + xs[k + 2] * w.z + xs[k + 3] * w.w;
  }
  x2[b * 256 + n] = fmaxf(acc, 0.0f);
}

// ---------------------------------------------------------------------------
// Kernel 5: out = x2 @ W3^T + b3
// ---------------------------------------------------------------------------
__global__ __launch_bounds__(128) void fc3_kernel(
    const float* __restrict__ x2, const float* __restrict__ W3,
    const float* __restrict__ b3, float* __restrict__ out) {
  __shared__ float xs[256];
  int b = blockIdx.x, n = threadIdx.x;
  xs[n] = x2[b * 256 + n];
  xs[n + 128] = x2[b * 256 + 128 + n];
  __syncthreads();
  float acc = b3[n];
  const float* wr = W3 + (size_t)n * 256;
#pragma unroll 4
  for (int k = 0; k < 256; k += 4) {
    float4 w = *reinterpret_cast<const float4*>(wr + k);
    acc += xs[k] * w.x + xs[k + 1] * w.y + xs[k + 2] * w.z + xs[k + 3] * w.w;
  }
  out[b * 128 + n] = acc;
}

extern "C" void kernel_launch(void* const* d_in, const int* in_sizes, int n_in,
                              void* d_out, int out_size, void* d_ws, size_t ws_size,
                              hipStream_t stream) {
  const float* img = (const float*)d_in[0];
  const float* W1 = (const float*)d_in[1];
  const float* b1 = (const float*)d_in[2];
  const float* W2 = (const float*)d_in[3];
  const float* b2 = (const float*)d_in[4];
  const float* W3 = (const float*)d_in[5];
  const float* b3 = (const float*)d_in[6];
  float* out = (float*)d_out;
  char* ws = (char*)d_ws;

  const size_t FEATS_B = 50331648ull;  // bf16 [256][98304]
  const size_t TAIL_B = 524288ull + 262144ull;
  // S=64: grid 1024 = exactly 4 blocks/CU; partial 32MB. Fallback 32.
  int S = (ws_size >= FEATS_B + 64ull * 524288 + TAIL_B) ? 64 : 32;
  const int iters = IN_DIM / S / 32;  // 48 / 96

  unsigned short* feats = (unsigned short*)ws;
  float* partial = (float*)(ws + FEATS_B);
  float* x1 = partial + (size_t)S * 131072;
  float* x2 = x1 + 131072;

  hipLaunchKernelGGL(fft_feats_kernel, dim3(3, 256), dim3(1024), 0, stream, img, feats);
  hipLaunchKernelGGL(gemm1_kernel, dim3(16 * S), dim3(256), 0, stream,
                     feats, W1, partial, S, iters);
  hipLaunchKernelGGL(reduce1_kernel, dim3(512), dim3(256), 0, stream, partial, b1, x1, S);
  hipLaunchKernelGGL(fc2_kernel, dim3(256), dim3(256), 0, stream, x1, W2, b2, x2);
  hipLaunchKernelGGL(fc3_kernel, dim3(256), dim3(128), 0, stream, x2, W3, b3, out);
}

// Round 7
// 189.284 us; speedup vs baseline: 1.3108x; 1.0705x over previous
//
#include <hip/hip_runtime.h>
#include <hip/hip_bf16.h>

#define IN_DIM 98304

typedef short bh8 __attribute__((ext_vector_type(8)));
typedef float f32x4 __attribute__((ext_vector_type(4)));
typedef unsigned short u16x8 __attribute__((ext_vector_type(8)));

__device__ __forceinline__ unsigned short f2bf(float f) {
  __hip_bfloat16 h = __float2bfloat16(f);
  return __builtin_bit_cast(unsigned short, h);
}

__device__ __forceinline__ void gload_lds16(const void* g, void* l) {
  __builtin_amdgcn_global_load_lds(
      (const __attribute__((address_space(1))) void*)g,
      (__attribute__((address_space(3))) void*)l, 16, 0, 0);
}

__device__ __forceinline__ void bfly(float2& a, float2& b, float wr, float wi) {
  float tr = wr * b.x - wi * b.y;
  float ti = wr * b.y + wi * b.x;
  b.x = a.x - tr; b.y = a.y - ti;
  a.x += tr; a.y += ti;
}

__device__ __forceinline__ float2 cmul(float2 a, float2 w) {
  return make_float2(a.x * w.x - a.y * w.y, a.x * w.y + a.y * w.x);
}

// 16-point FFT, input bit-reversed in v[], output natural order.
__device__ __forceinline__ void fft16(float2* v) {
  const float C8 = 0.70710678118654752f;
  const float C161 = 0.92387953251128674f, S161 = 0.38268343236508977f;
#pragma unroll
  for (int i = 0; i < 16; i += 2) bfly(v[i], v[i + 1], 1.f, 0.f);
#pragma unroll
  for (int i = 0; i < 16; i += 4) {
    bfly(v[i], v[i + 2], 1.f, 0.f);
    bfly(v[i + 1], v[i + 3], 0.f, -1.f);
  }
  {
    const float w8r[4] = {1.f, C8, 0.f, -C8};
    const float w8i[4] = {0.f, -C8, -1.f, -C8};
#pragma unroll
    for (int i = 0; i < 16; i += 8) {
#pragma unroll
      for (int j = 0; j < 4; ++j) bfly(v[i + j], v[i + j + 4], w8r[j], w8i[j]);
    }
  }
  {
    const float w16r[8] = {1.f, C161, C8, S161, 0.f, -S161, -C8, -C161};
    const float w16i[8] = {0.f, -S161, -C8, -C161, -1.f, -C161, -C8, -S161};
#pragma unroll
    for (int j = 0; j < 8; ++j) bfly(v[j], v[j + 8], w16r[j], w16i[j]);
  }
}

// 8-point FFT, input bit-reversed in v[], output natural order.
__device__ __forceinline__ void fft8(float2* v) {
  const float C8 = 0.70710678118654752f;
#pragma unroll
  for (int i = 0; i < 8; i += 2) bfly(v[i], v[i + 1], 1.f, 0.f);
#pragma unroll
  for (int i = 0; i < 8; i += 4) {
    bfly(v[i], v[i + 2], 1.f, 0.f);
    bfly(v[i + 1], v[i + 3], 0.f, -1.f);
  }
  bfly(v[0], v[4], 1.f, 0.f);
  bfly(v[1], v[5], C8, -C8);
  bfly(v[2], v[6], 0.f, -1.f);
  bfly(v[3], v[7], -C8, -C8);
}

// swizzled LDS index (float2 units)
__device__ __forceinline__ int IDX(int r, int cc) {
  return (r << 7) + (cc ^ ((r & 7) << 1));
}

// ---------------------------------------------------------------------------
// Kernel 1: 128x128 FFT2 + fftshift + amp/phase -> bf16 feats. 1024 threads.
// ---------------------------------------------------------------------------
__global__ __launch_bounds__(1024) void fft_feats_kernel(
    const float* __restrict__ img, unsigned short* __restrict__ feats) {
  __shared__ float2 sm[16384];
  __shared__ float2 tw[128];
  const int tid = threadIdx.x;
  const int c = blockIdx.x, b = blockIdx.y;
  const float* src = img + ((size_t)(b * 3 + c) << 14);

  static const int BR4[16] = {0, 8, 4, 12, 2, 10, 6, 14, 1, 9, 5, 13, 3, 11, 7, 15};
  static const int BR3[8] = {0, 4, 2, 6, 1, 5, 3, 7};

  if (tid < 128) {
    float sv, cv;
    sincosf(-6.28318530717958647692f * (float)tid / 128.0f, &sv, &cv);
    tw[tid] = make_float2(cv, sv);
  }
#pragma unroll
  for (int i4 = tid; i4 < 4096; i4 += 1024) {
    float4 x = *reinterpret_cast<const float4*>(src + (i4 << 2));
    int r = i4 >> 5, cc = (i4 << 2) & 127;
    *reinterpret_cast<float4*>(&sm[IDX(r, cc)]) = make_float4(x.x, 0.f, x.y, 0.f);
    *reinterpret_cast<float4*>(&sm[IDX(r, cc + 2)]) = make_float4(x.z, 0.f, x.w, 0.f);
  }
  __syncthreads();

  // ---- row pass, stage 1: slot (r, n2)
  {
    int r = tid >> 3, n2 = tid & 7;
    float2 v[16];
#pragma unroll
    for (int j = 0; j < 16; ++j) v[j] = sm[IDX(r, (BR4[j] << 3) + n2)];
    fft16(v);
#pragma unroll
    for (int k1 = 1; k1 < 16; ++k1) v[k1] = cmul(v[k1], tw[n2 * k1]);
#pragma unroll
    for (int k1 = 0; k1 < 16; ++k1) sm[IDX(r, (k1 << 3) + n2)] = v[k1];
  }
  __syncthreads();

  // ---- row pass, stage 2: slot (r, t8)
  {
    int r = tid >> 3, t8 = tid & 7;
    float2 u0[8], u1[8];
#pragma unroll
    for (int j = 0; j < 8; ++j) {
      u0[j] = sm[IDX(r, (t8 << 3) + BR3[j])];
      u1[j] = sm[IDX(r, ((t8 + 8) << 3) + BR3[j])];
    }
    __syncthreads();  // all reads before any writes
    fft8(u0);
    fft8(u1);
#pragma unroll
    for (int k2 = 0; k2 < 8; ++k2) {
      sm[IDX(r, t8 + (k2 << 4))] = u0[k2];
      sm[IDX(r, t8 + 8 + (k2 << 4))] = u1[k2];
    }
  }
  __syncthreads();

  // ---- col pass, stage 1: slot (col, n2)
  {
    int col = tid & 127, n2 = tid >> 7;
    float2 v[16];
#pragma unroll
    for (int j = 0; j < 16; ++j) v[j] = sm[IDX((BR4[j] << 3) + n2, col)];
    fft16(v);
#pragma unroll
    for (int k1 = 1; k1 < 16; ++k1) v[k1] = cmul(v[k1], tw[n2 * k1]);
#pragma unroll
    for (int k1 = 0; k1 < 16; ++k1) sm[IDX((k1 << 3) + n2, col)] = v[k1];
  }
  __syncthreads();

  // ---- col pass, stage 2 + fftshift + amp/phase + global write
  unsigned short* dst = feats + (size_t)b * IN_DIM + c * 32768;
  {
    int col = tid & 127, t8 = tid >> 7;
    float2 u0[8], u1[8];
#pragma unroll
    for (int j = 0; j < 8; ++j) {
      u0[j] = sm[IDX((t8 << 3) + BR3[j], col)];
      u1[j] = sm[IDX(((t8 + 8) << 3) + BR3[j], col)];
    }
    fft8(u0);
    fft8(u1);
    int ow = col ^ 64;
#pragma unroll
    for (int k2 = 0; k2 < 8; ++k2) {
      int oh0 = (t8 + (k2 << 4)) ^ 64;
      int oh1 = (t8 + 8 + (k2 << 4)) ^ 64;
      float a0 = sqrtf(u0[k2].x * u0[k2].x + u0[k2].y * u0[k2].y);
      float p0 = atan2f(u0[k2].y, u0[k2].x);
      float a1 = sqrtf(u1[k2].x * u1[k2].x + u1[k2].y * u1[k2].y);
      float p1 = atan2f(u1[k2].y, u1[k2].x);
      dst[(oh0 << 7) + ow] = f2bf(a0);
      dst[16384 + (oh0 << 7) + ow] = f2bf(p0);
      dst[(oh1 << 7) + ow] = f2bf(a1);
      dst[16384 + (oh1 << 7) + ow] = f2bf(p1);
    }
  }
}

// ---------------------------------------------------------------------------
// Kernel 2: layer-1 GEMM, split-K + split-M. DEPTH-4 pipeline (3 tiles in
// flight), ONE s_barrier per K-step, counted vmcnt(12/8/4/0).
// MT=128, NT=64, BK=32, grid 16*S = 512 @ S=32 -> exactly 2 blocks/CU
// (64KB LDS each). Both A and B staged via global_load_lds with
// source-side inverse XOR swizzle (A: slot^=row&3, B: slot^=row&7) so
// ds_read_b128 fragment reads are bank-conflict-free.
// Race-freedom (1 barrier): barrier at top of iter k guarantees all waves
// finished ds_reads of buf[(k-1)&3]; stage(k+3) (issued after that
// barrier) targets exactly buf[(k+3)&3] == buf[(k-1)&3]. Per-wave
// vmcnt(12) before the barrier => every wave's stage(k) has landed.
// ---------------------------------------------------------------------------
__global__ __launch_bounds__(256, 2) void gemm1_kernel(
    const unsigned short* __restrict__ feats, const float* __restrict__ W1,
    float* __restrict__ partial, int S, int iters) {
  __shared__ __align__(16) unsigned short Asm[4][128 * 32];  // 4 x 8 KB bf16
  __shared__ __align__(16) float Bsm[4][64 * 32];            // 4 x 8 KB fp32
  const int tid = threadIdx.x;
  const int wv = tid >> 6, lane = tid & 63;

  // XCD-aware decode: the 16 blocks sharing a ks land on one XCD.
  const int f = blockIdx.x;
  const int kpx = S >> 3;
  const int xcd = f & 7, g = f >> 3;
  const int ks = xcd * kpx + (g % kpx);
  const int t = g / kpx;  // 0..15
  const int mt = t & 1, nt = t >> 1;
  const int m0 = mt * 128, n0 = nt * 64;
  const size_t k0 = (size_t)ks * ((size_t)iters * 32);

  // A staging: chunk s covers rows s*16..+15; lane -> row s*16+(l>>2).
  // Source inverse swizzle: lane's phys slot (l&3) gets global slot
  // (l&3)^(row&3). (row&3 == (l>>2)&3.)
  const int al_row = lane >> 2;
  const int al_k = ((lane & 3) ^ (al_row & 3)) * 8;  // bf16 elems
  // B staging: chunk s covers rows s*8..+7; lane -> row s*8+(l>>3).
  // Source inverse swizzle: phys slot (l&7) gets global f4 (l&7)^(row&7).
  const int bl_row = lane >> 3;
  const int bl_f = ((lane & 7) ^ bl_row) * 4;  // fp32 elems

  f32x4 acc[2][4];
#pragma unroll
  for (int i = 0; i < 2; ++i)
#pragma unroll
    for (int jj = 0; jj < 4; ++jj) acc[i][jj] = (f32x4){0.f, 0.f, 0.f, 0.f};

  auto stage = [&](int buf, int it) {
    const size_t kb = k0 + (size_t)it * 32;
#pragma unroll
    for (int tl = 0; tl < 2; ++tl) {
      const int s = wv * 2 + tl;  // 0..7
      const unsigned short* ga =
          feats + (size_t)(m0 + s * 16 + al_row) * IN_DIM + kb + al_k;
      gload_lds16(ga, (char*)&Asm[buf][0] + s * 1024);
      const float* gb = W1 + (size_t)(n0 + s * 8 + bl_row) * IN_DIM + kb + bl_f;
      gload_lds16(gb, (char*)&Bsm[buf][0] + s * 1024);
    }
  };

  stage(0, 0);
  stage(1, 1);
  stage(2, 2);

  const int rm = lane & 15, hi = lane >> 4;

  for (int k = 0; k < iters; ++k) {
    const int buf = k & 3;
    const int rem = iters - 1 - k;
    if (rem >= 3) {
      asm volatile("s_waitcnt vmcnt(12)" ::: "memory");
    } else if (rem == 2) {
      asm volatile("s_waitcnt vmcnt(8)" ::: "memory");
    } else if (rem == 1) {
      asm volatile("s_waitcnt vmcnt(4)" ::: "memory");
    } else {
      asm volatile("s_waitcnt vmcnt(0)" ::: "memory");
    }
    __builtin_amdgcn_sched_barrier(0);
    __builtin_amdgcn_s_barrier();
    __builtin_amdgcn_sched_barrier(0);

    // ds_read fragment loads (bank-conflict-free via swizzle)
    bh8 afr[2];
    f32x4 braw[4][2];
#pragma unroll
    for (int i = 0; i < 2; ++i) {
      const int row = wv * 32 + i * 16 + rm;
      afr[i] = *reinterpret_cast<const bh8*>(
          &Asm[buf][row * 32 + ((hi ^ (row & 3)) * 8)]);
    }
#pragma unroll
    for (int jj = 0; jj < 4; ++jj) {
      const int r = jj * 16 + rm;
      const int rb = r * 32;
      braw[jj][0] = *reinterpret_cast<const f32x4*>(
          &Bsm[buf][rb + (((hi * 2 + 0) ^ (r & 7)) * 4)]);
      braw[jj][1] = *reinterpret_cast<const f32x4*>(
          &Bsm[buf][rb + (((hi * 2 + 1) ^ (r & 7)) * 4)]);
    }
    __builtin_amdgcn_sched_barrier(0);

    // prefetch 3 tiles ahead (targets buf[(k+3)&3] == buf[(k-1)&3], safe
    // per the barrier above; loads fly over the MFMA cluster below)
    if (k + 3 < iters) stage((k + 3) & 3, k + 3);

    asm volatile("s_waitcnt lgkmcnt(0)" ::: "memory");
    __builtin_amdgcn_sched_barrier(0);

    bh8 bfr[4];
#pragma unroll
    for (int jj = 0; jj < 4; ++jj) {
#pragma unroll
      for (int p = 0; p < 4; ++p) {
        bfr[jj][p] = (short)f2bf(braw[jj][0][p]);
        bfr[jj][4 + p] = (short)f2bf(braw[jj][1][p]);
      }
    }
#pragma unroll
    for (int i = 0; i < 2; ++i)
#pragma unroll
      for (int jj = 0; jj < 4; ++jj)
        acc[i][jj] = __builtin_amdgcn_mfma_f32_16x16x32_bf16(
            afr[i], bfr[jj], acc[i][jj], 0, 0, 0);
  }

  // epilogue: C/D layout col=lane&15, row=(lane>>4)*4+reg (m89-verified)
  const int rg = lane >> 4;
  float* pbase = partial + ((size_t)ks << 17);
#pragma unroll
  for (int i = 0; i < 2; ++i) {
#pragma unroll
    for (int jj = 0; jj < 4; ++jj) {
      const int n = n0 + jj * 16 + rm;
#pragma unroll
      for (int r = 0; r < 4; ++r) {
        const int m = m0 + wv * 32 + i * 16 + rg * 4 + r;
        pbase[((size_t)m << 9) + n] = acc[i][jj][r];
      }
    }
  }
}

// ---------------------------------------------------------------------------
// Kernel 3: reduce split-K partials + bias + ReLU -> x1 [256][512] fp32
// ---------------------------------------------------------------------------
__global__ __launch_bounds__(256) void reduce1_kernel(
    const float* __restrict__ partial, const float* __restrict__ b1,
    float* __restrict__ x1, int S) {
  int i = blockIdx.x * 256 + threadIdx.x;  // 0..131071
  float s = b1[i & 511];
  for (int p = 0; p < S; ++p) s += partial[((size_t)p << 17) + i];
  x1[i] = fmaxf(s, 0.0f);
}

// ---------------------------------------------------------------------------
// Kernel 4: x2 = relu(x1 @ W2^T + b2)
// ---------------------------------------------------------------------------
__global__ __launch_bounds__(256) void fc2_kernel(
    const float* __restrict__ x1, const float* __restrict__ W2,
    const float* __restrict__ b2, float* __restrict__ x2) {
  __shared__ float xs[512];
  int b = blockIdx.x, n = threadIdx.x;
  xs[n] = x1[b * 512 + n];
  xs[n + 256] = x1[b * 512 + 256 + n];
  __syncthreads();
  float acc = b2[n];
  const float* wr = W2 + (size_t)n * 512;
#pragma unroll 4
  for (int k = 0; k < 512; k += 4) {
    float4 w = *reinterpret_cast<const float4*>(wr + k);
    acc += xs[k] * w.x + xs[k + 1] * w.y + xs[k + 2] * w.z + xs[k + 3] * w.w;
  }
  x2[b * 256 + n] = fmaxf(acc, 0.0f);
}

// ---------------------------------------------------------------------------
// Kernel 5: out = x2 @ W3^T + b3
// ---------------------------------------------------------------------------
__global__ __launch_bounds__(128) void fc3_kernel(
    const float* __restrict__ x2, const float* __restrict__ W3,
    const float* __restrict__ b3, float* __restrict__ out) {
  __shared__ float xs[256];
  int b = blockIdx.x, n = threadIdx.x;
  xs[n] = x2[b * 256 + n];
  xs[n + 128] = x2[b * 256 + 128 + n];
  __syncthreads();
  float acc = b3[n];
  const float* wr = W3 + (size_t)n * 256;
#pragma unroll 4
  for (int k = 0; k < 256; k += 4) {
    float4 w = *reinterpret_cast<const float4*>(wr + k);
    acc += xs[k] * w.x + xs[k + 1] * w.y + xs[k + 2] * w.z + xs[k + 3] * w.w;
  }
  out[b * 128 + n] = acc;
}

extern "C" void kernel_launch(void* const* d_in, const int* in_sizes, int n_in,
                              void* d_out, int out_size, void* d_ws, size_t ws_size,
                              hipStream_t stream) {
  const float* img = (const float*)d_in[0];
  const float* W1 = (const float*)d_in[1];
  const float* b1 = (const float*)d_in[2];
  const float* W2 = (const float*)d_in[3];
  const float* b2 = (const float*)d_in[4];
  const float* W3 = (const float*)d_in[5];
  const float* b3 = (const float*)d_in[6];
  float* out = (float*)d_out;
  char* ws = (char*)d_ws;

  const size_t FEATS_B = 50331648ull;  // bf16 [256][98304]
  // S=32: grid 512 = exactly 2 blocks/CU (64KB LDS); partial 16MB.
  const int S = 32;
  const int iters = IN_DIM / S / 32;  // 96

  unsigned short* feats = (unsigned short*)ws;
  float* partial = (float*)(ws + FEATS_B);
  float* x1 = partial + (size_t)S * 131072;
  float* x2 = x1 + 131072;

  hipLaunchKernelGGL(fft_feats_kernel, dim3(3, 256), dim3(1024), 0, stream, img, feats);
  hipLaunchKernelGGL(gemm1_kernel, dim3(16 * S), dim3(256), 0, stream,
                     feats, W1, partial, S, iters);
  hipLaunchKernelGGL(reduce1_kernel, dim3(512), dim3(256), 0, stream, partial, b1, x1, S);
  hipLaunchKernelGGL(fc2_kernel, dim3(256), dim3(256), 0, stream, x1, W2, b2, x2);
  hipLaunchKernelGGL(fc3_kernel, dim3(256), dim3(128), 0, stream, x2, W3, b3, out);
}

// Round 8
// 168.954 us; speedup vs baseline: 1.4685x; 1.1203x over previous
//
#include <hip/hip_runtime.h>
#include <hip/hip_bf16.h>

#define IN_DIM 98304

typedef short bh8 __attribute__((ext_vector_type(8)));
typedef float f32x4 __attribute__((ext_vector_type(4)));
typedef unsigned short u16x8 __attribute__((ext_vector_type(8)));

__device__ __forceinline__ unsigned short f2bf(float f) {
  __hip_bfloat16 h = __float2bfloat16(f);
  return __builtin_bit_cast(unsigned short, h);
}

__device__ __forceinline__ void gload_lds16(const void* g, void* l) {
  __builtin_amdgcn_global_load_lds(
      (const __attribute__((address_space(1))) void*)g,
      (__attribute__((address_space(3))) void*)l, 16, 0, 0);
}

__device__ __forceinline__ void bfly(float2& a, float2& b, float wr, float wi) {
  float tr = wr * b.x - wi * b.y;
  float ti = wr * b.y + wi * b.x;
  b.x = a.x - tr; b.y = a.y - ti;
  a.x += tr; a.y += ti;
}

__device__ __forceinline__ float2 cmul(float2 a, float2 w) {
  return make_float2(a.x * w.x - a.y * w.y, a.x * w.y + a.y * w.x);
}

// 16-point FFT, input bit-reversed in v[], output natural order.
__device__ __forceinline__ void fft16(float2* v) {
  const float C8 = 0.70710678118654752f;
  const float C161 = 0.92387953251128674f, S161 = 0.38268343236508977f;
#pragma unroll
  for (int i = 0; i < 16; i += 2) bfly(v[i], v[i + 1], 1.f, 0.f);
#pragma unroll
  for (int i = 0; i < 16; i += 4) {
    bfly(v[i], v[i + 2], 1.f, 0.f);
    bfly(v[i + 1], v[i + 3], 0.f, -1.f);
  }
  {
    const float w8r[4] = {1.f, C8, 0.f, -C8};
    const float w8i[4] = {0.f, -C8, -1.f, -C8};
#pragma unroll
    for (int i = 0; i < 16; i += 8) {
#pragma unroll
      for (int j = 0; j < 4; ++j) bfly(v[i + j], v[i + j + 4], w8r[j], w8i[j]);
    }
  }
  {
    const float w16r[8] = {1.f, C161, C8, S161, 0.f, -S161, -C8, -C161};
    const float w16i[8] = {0.f, -S161, -C8, -C161, -1.f, -C161, -C8, -S161};
#pragma unroll
    for (int j = 0; j < 8; ++j) bfly(v[j], v[j + 8], w16r[j], w16i[j]);
  }
}

// 8-point FFT, input bit-reversed in v[], output natural order.
__device__ __forceinline__ void fft8(float2* v) {
  const float C8 = 0.70710678118654752f;
#pragma unroll
  for (int i = 0; i < 8; i += 2) bfly(v[i], v[i + 1], 1.f, 0.f);
#pragma unroll
  for (int i = 0; i < 8; i += 4) {
    bfly(v[i], v[i + 2], 1.f, 0.f);
    bfly(v[i + 1], v[i + 3], 0.f, -1.f);
  }
  bfly(v[0], v[4], 1.f, 0.f);
  bfly(v[1], v[5], C8, -C8);
  bfly(v[2], v[6], 0.f, -1.f);
  bfly(v[3], v[7], -C8, -C8);
}

// swizzled LDS index (float2 units)
__device__ __forceinline__ int IDX(int r, int cc) {
  return (r << 7) + (cc ^ ((r & 7) << 1));
}

// ---------------------------------------------------------------------------
// Kernel 1: 128x128 FFT2 + fftshift + amp/phase -> bf16 feats. 1024 threads.
// ---------------------------------------------------------------------------
__global__ __launch_bounds__(1024) void fft_feats_kernel(
    const float* __restrict__ img, unsigned short* __restrict__ feats) {
  __shared__ float2 sm[16384];
  __shared__ float2 tw[128];
  const int tid = threadIdx.x;
  const int c = blockIdx.x, b = blockIdx.y;
  const float* src = img + ((size_t)(b * 3 + c) << 14);

  static const int BR4[16] = {0, 8, 4, 12, 2, 10, 6, 14, 1, 9, 5, 13, 3, 11, 7, 15};
  static const int BR3[8] = {0, 4, 2, 6, 1, 5, 3, 7};

  if (tid < 128) {
    float sv, cv;
    sincosf(-6.28318530717958647692f * (float)tid / 128.0f, &sv, &cv);
    tw[tid] = make_float2(cv, sv);
  }
#pragma unroll
  for (int i4 = tid; i4 < 4096; i4 += 1024) {
    float4 x = *reinterpret_cast<const float4*>(src + (i4 << 2));
    int r = i4 >> 5, cc = (i4 << 2) & 127;
    *reinterpret_cast<float4*>(&sm[IDX(r, cc)]) = make_float4(x.x, 0.f, x.y, 0.f);
    *reinterpret_cast<float4*>(&sm[IDX(r, cc + 2)]) = make_float4(x.z, 0.f, x.w, 0.f);
  }
  __syncthreads();

  // ---- row pass, stage 1: slot (r, n2)
  {
    int r = tid >> 3, n2 = tid & 7;
    float2 v[16];
#pragma unroll
    for (int j = 0; j < 16; ++j) v[j] = sm[IDX(r, (BR4[j] << 3) + n2)];
    fft16(v);
#pragma unroll
    for (int k1 = 1; k1 < 16; ++k1) v[k1] = cmul(v[k1], tw[n2 * k1]);
#pragma unroll
    for (int k1 = 0; k1 < 16; ++k1) sm[IDX(r, (k1 << 3) + n2)] = v[k1];
  }
  __syncthreads();

  // ---- row pass, stage 2: slot (r, t8)
  {
    int r = tid >> 3, t8 = tid & 7;
    float2 u0[8], u1[8];
#pragma unroll
    for (int j = 0; j < 8; ++j) {
      u0[j] = sm[IDX(r, (t8 << 3) + BR3[j])];
      u1[j] = sm[IDX(r, ((t8 + 8) << 3) + BR3[j])];
    }
    __syncthreads();  // all reads before any writes
    fft8(u0);
    fft8(u1);
#pragma unroll
    for (int k2 = 0; k2 < 8; ++k2) {
      sm[IDX(r, t8 + (k2 << 4))] = u0[k2];
      sm[IDX(r, t8 + 8 + (k2 << 4))] = u1[k2];
    }
  }
  __syncthreads();

  // ---- col pass, stage 1: slot (col, n2)
  {
    int col = tid & 127, n2 = tid >> 7;
    float2 v[16];
#pragma unroll
    for (int j = 0; j < 16; ++j) v[j] = sm[IDX((BR4[j] << 3) + n2, col)];
    fft16(v);
#pragma unroll
    for (int k1 = 1; k1 < 16; ++k1) v[k1] = cmul(v[k1], tw[n2 * k1]);
#pragma unroll
    for (int k1 = 0; k1 < 16; ++k1) sm[IDX((k1 << 3) + n2, col)] = v[k1];
  }
  __syncthreads();

  // ---- col pass, stage 2 + fftshift + amp/phase + global write
  unsigned short* dst = feats + (size_t)b * IN_DIM + c * 32768;
  {
    int col = tid & 127, t8 = tid >> 7;
    float2 u0[8], u1[8];
#pragma unroll
    for (int j = 0; j < 8; ++j) {
      u0[j] = sm[IDX((t8 << 3) + BR3[j], col)];
      u1[j] = sm[IDX(((t8 + 8) << 3) + BR3[j], col)];
    }
    fft8(u0);
    fft8(u1);
    int ow = col ^ 64;
#pragma unroll
    for (int k2 = 0; k2 < 8; ++k2) {
      int oh0 = (t8 + (k2 << 4)) ^ 64;
      int oh1 = (t8 + 8 + (k2 << 4)) ^ 64;
      float a0 = sqrtf(u0[k2].x * u0[k2].x + u0[k2].y * u0[k2].y);
      float p0 = atan2f(u0[k2].y, u0[k2].x);
      float a1 = sqrtf(u1[k2].x * u1[k2].x + u1[k2].y * u1[k2].y);
      float p1 = atan2f(u1[k2].y, u1[k2].x);
      dst[(oh0 << 7) + ow] = f2bf(a0);
      dst[16384 + (oh0 << 7) + ow] = f2bf(p0);
      dst[(oh1 << 7) + ow] = f2bf(a1);
      dst[16384 + (oh1 << 7) + ow] = f2bf(p1);
    }
  }
}

// ---------------------------------------------------------------------------
// Kernel 2: layer-1 GEMM, MINIMUM-TRAFFIC tiling. MT=256 (full M), NT=128,
// S=64 split-K -> grid 256 = 1 block/CU, 512 threads (8 waves = 2/SIMD).
// A read ONCE from HBM (4 same-ks blocks share chunks via XCD decode),
// B (W1 fp32) read ONCE: total ~290MB vs R7's 802MB replicated.
// A: global_load_lds, 4 buffers, staged 3 ahead. B: reg-staged fp32,
// converted to bf16 ONCE per tile (8 f2bf/thread), ds_write, 2 buffers.
// One s_barrier per iter. Counted vmcnt: mid-body vmcnt(2) forces loads
// from ~1.2 iters ago (iter ~2400cy >> 900cy latency => no stall).
// ---------------------------------------------------------------------------
#define GS 64     // split-K factor
#define GITERS 48 // 98304 / 64 / 32

__global__ __launch_bounds__(512, 2) void gemm1_kernel(
    const unsigned short* __restrict__ feats, const float* __restrict__ W1,
    float* __restrict__ partial) {
  __shared__ __align__(16) unsigned short Asm[4][256 * 32];  // 4 x 16 KB
  __shared__ __align__(16) unsigned short Bsm[2][128 * 32];  // 2 x 8 KB
  const int tid = threadIdx.x;
  const int wv = tid >> 6, lane = tid & 63;

  // XCD decode: 4 blocks sharing ks (nt=0..3) land on one XCD -> A L2 reuse.
  const int f = blockIdx.x;
  const int xcd = f & 7, v = f >> 3;       // v: 0..31
  const int ks = xcd * 8 + (v & 7);        // 0..63
  const int nt = v >> 3;                   // 0..3
  const int n0 = nt * 128;
  const size_t k0 = (size_t)ks * (GITERS * 32);

  // A staging: 16 chunks of 1KB; wave stages chunks 2wv, 2wv+1.
  const int al_row = lane >> 2;
  const int al_k = (lane & 3) * 8;
  // B reg staging: thread -> row tid>>2 (0..127), quarter tid&3.
  const int brow = tid >> 2, bq = tid & 3;
  const float* bsrc = W1 + (size_t)(n0 + brow) * IN_DIM + k0 + bq * 8;

  auto stageA = [&](int buf, int it) {
    const size_t kb = k0 + (size_t)it * 32;
#pragma unroll
    for (int tl = 0; tl < 2; ++tl) {
      const int s = wv * 2 + tl;  // 0..15
      const unsigned short* ga =
          feats + (size_t)(s * 16 + al_row) * IN_DIM + kb + al_k;
      gload_lds16(ga, (char*)&Asm[buf][0] + s * 1024);
    }
  };

  float4 br0, br1;  // B in-flight regs
  auto loadB = [&](int it) {
    const float* p = bsrc + (size_t)it * 32;
    br0 = *reinterpret_cast<const float4*>(p);
    br1 = *reinterpret_cast<const float4*>(p + 4);
  };
  auto writeB = [&](int buf) {
    u16x8 bw;
    bw[0] = f2bf(br0.x); bw[1] = f2bf(br0.y); bw[2] = f2bf(br0.z); bw[3] = f2bf(br0.w);
    bw[4] = f2bf(br1.x); bw[5] = f2bf(br1.y); bw[6] = f2bf(br1.z); bw[7] = f2bf(br1.w);
    *reinterpret_cast<u16x8*>(&Bsm[buf][brow * 32 + bq * 8]) = bw;
  };

  f32x4 acc[4][4];
#pragma unroll
  for (int i = 0; i < 4; ++i)
#pragma unroll
    for (int jj = 0; jj < 4; ++jj) acc[i][jj] = (f32x4){0.f, 0.f, 0.f, 0.f};

  // wave -> output sub-tile: 4 M-quarters x 2 N-halves
  const int mr = wv & 3;   // 64-row M slice
  const int nc = wv >> 2;  // 64-col N slice
  const int rm = lane & 15, hi = lane >> 4;

  // prologue
  stageA(0, 0);
  stageA(1, 1);
  stageA(2, 2);
  loadB(0);
  asm volatile("s_waitcnt vmcnt(0)" ::: "memory");
  writeB(0);
  loadB(1);

  for (int k = 0; k < GITERS; ++k) {
    const int rem = GITERS - 1 - k;
    if (rem >= 1) {
      asm volatile("s_waitcnt vmcnt(4) lgkmcnt(0)" ::: "memory");
    } else {
      asm volatile("s_waitcnt vmcnt(0) lgkmcnt(0)" ::: "memory");
    }
    __builtin_amdgcn_sched_barrier(0);
    __builtin_amdgcn_s_barrier();
    __builtin_amdgcn_sched_barrier(0);

    // fragment ds_reads
    const int abuf = k & 3, bbuf = k & 1;
    bh8 afr[4], bfr[4];
#pragma unroll
    for (int i = 0; i < 4; ++i) {
      const int row = mr * 64 + i * 16 + rm;
      afr[i] = *reinterpret_cast<const bh8*>(&Asm[abuf][row * 32 + hi * 8]);
    }
#pragma unroll
    for (int jj = 0; jj < 4; ++jj) {
      const int row = nc * 64 + jj * 16 + rm;
      bfr[jj] = *reinterpret_cast<const bh8*>(&Bsm[bbuf][row * 32 + hi * 8]);
    }
    __builtin_amdgcn_sched_barrier(0);

    // A prefetch 3 ahead (targets bufA[(k+3)&3] == bufA[(k-1)&3]; all waves
    // finished reading it before the barrier above)
    if (rem >= 3) stageA((k + 3) & 3, k + 3);

    if (rem >= 1) {
      // force B regs for tile k+1 (issued ~1.2 iters ago) to have landed
      if (rem >= 3) {
        asm volatile("s_waitcnt vmcnt(2)" ::: "memory");
      } else {
        asm volatile("s_waitcnt vmcnt(0)" ::: "memory");
      }
      __builtin_amdgcn_sched_barrier(0);
      writeB((k + 1) & 1);       // convert fp32->bf16 once, write next B buf
      if (rem >= 2) loadB(k + 2);  // issue next B reg-load (consumed at k+1)
    }

    // fragment reads complete (the one ds_write may stay outstanding)
    asm volatile("s_waitcnt lgkmcnt(1)" ::: "memory");
    __builtin_amdgcn_sched_barrier(0);

#pragma unroll
    for (int i = 0; i < 4; ++i)
#pragma unroll
      for (int jj = 0; jj < 4; ++jj)
        acc[i][jj] = __builtin_amdgcn_mfma_f32_16x16x32_bf16(
            afr[i], bfr[jj], acc[i][jj], 0, 0, 0);
  }

  // epilogue: C/D layout col=lane&15, row=(lane>>4)*4+reg (m89-verified)
  const int rg = lane >> 4;
  float* pbase = partial + ((size_t)ks << 17);
#pragma unroll
  for (int i = 0; i < 4; ++i) {
#pragma unroll
    for (int jj = 0; jj < 4; ++jj) {
      const int n = n0 + nc * 64 + jj * 16 + rm;
#pragma unroll
      for (int r = 0; r < 4; ++r) {
        const int m = mr * 64 + i * 16 + rg * 4 + r;
        pbase[((size_t)m << 9) + n] = acc[i][jj][r];
      }
    }
  }
}

// ---------------------------------------------------------------------------
// Kernel 3: reduce split-K partials + bias + ReLU -> x1 [256][512] fp32
// ---------------------------------------------------------------------------
__global__ __launch_bounds__(256) void reduce1_kernel(
    const float* __restrict__ partial, const float* __restrict__ b1,
    float* __restrict__ x1, int S) {
  int i = blockIdx.x * 256 + threadIdx.x;  // 0..131071
  float s = b1[i & 511];
  for (int p = 0; p < S; ++p) s += partial[((size_t)p << 17) + i];
  x1[i] = fmaxf(s, 0.0f);
}

// ---------------------------------------------------------------------------
// Kernel 4: x2 = relu(x1 @ W2^T + b2)
// ---------------------------------------------------------------------------
__global__ __launch_bounds__(256) void fc2_kernel(
    const float* __restrict__ x1, const float* __restrict__ W2,
    const float* __restrict__ b2, float* __restrict__ x2) {
  __shared__ float xs[512];
  int b = blockIdx.x, n = threadIdx.x;
  xs[n] = x1[b * 512 + n];
  xs[n + 256] = x1[b * 512 + 256 + n];
  __syncthreads();
  float acc = b2[n];
  const float* wr = W2 + (size_t)n * 512;
#pragma unroll 4
  for (int k = 0; k < 512; k += 4) {
    float4 w = *reinterpret_cast<const float4*>(wr + k);
    acc += xs[k] * w.x + xs[k + 1] * w.y + xs[k + 2] * w.z + xs[k + 3] * w.w;
  }
  x2[b * 256 + n] = fmaxf(acc, 0.0f);
}

// ---------------------------------------------------------------------------
// Kernel 5: out = x2 @ W3^T + b3
// ---------------------------------------------------------------------------
__global__ __launch_bounds__(128) void fc3_kernel(
    const float* __restrict__ x2, const float* __restrict__ W3,
    const float* __restrict__ b3, float* __restrict__ out) {
  __shared__ float xs[256];
  int b = blockIdx.x, n = threadIdx.x;
  xs[n] = x2[b * 256 + n];
  xs[n + 128] = x2[b * 256 + 128 + n];
  __syncthreads();
  float acc = b3[n];
  const float* wr = W3 + (size_t)n * 256;
#pragma unroll 4
  for (int k = 0; k < 256; k += 4) {
    float4 w = *reinterpret_cast<const float4*>(wr + k);
    acc += xs[k] * w.x + xs[k + 1] * w.y + xs[k + 2] * w.z + xs[k + 3] * w.w;
  }
  out[b * 128 + n] = acc;
}

extern "C" void kernel_launch(void* const* d_in, const int* in_sizes, int n_in,
                              void* d_out, int out_size, void* d_ws, size_t ws_size,
                              hipStream_t stream) {
  const float* img = (const float*)d_in[0];
  const float* W1 = (const float*)d_in[1];
  const float* b1 = (const float*)d_in[2];
  const float* W2 = (const float*)d_in[3];
  const float* b2 = (const float*)d_in[4];
  const float* W3 = (const float*)d_in[5];
  const float* b3 = (const float*)d_in[6];
  float* out = (float*)d_out;
  char* ws = (char*)d_ws;

  const size_t FEATS_B = 50331648ull;  // bf16 [256][98304]
  // S=64 partials (32MB). R3's run proved ws >= 185MB, so this fits.
  unsigned short* feats = (unsigned short*)ws;
  float* partial = (float*)(ws + FEATS_B);
  float* x1 = partial + (size_t)GS * 131072;
  float* x2 = x1 + 131072;

  hipLaunchKernelGGL(fft_feats_kernel, dim3(3, 256), dim3(1024), 0, stream, img, feats);
  hipLaunchKernelGGL(gemm1_kernel, dim3(256), dim3(512), 0, stream, feats, W1, partial);
  hipLaunchKernelGGL(reduce1_kernel, dim3(512), dim3(256), 0, stream, partial, b1, x1, GS);
  hipLaunchKernelGGL(fc2_kernel, dim3(256), dim3(256), 0, stream, x1, W2, b2, x2);
  hipLaunchKernelGGL(fc3_kernel, dim3(256), dim3(128), 0, stream, x2, W3, b3, out);
}

// Round 9
// 151.551 us; speedup vs baseline: 1.6371x; 1.1148x over previous
//
#include <hip/hip_runtime.h>
#include <hip/hip_bf16.h>

#define IN_DIM 98304

typedef short bh8 __attribute__((ext_vector_type(8)));
typedef float f32x4 __attribute__((ext_vector_type(4)));
typedef unsigned short u16x8 __attribute__((ext_vector_type(8)));

__device__ __forceinline__ unsigned short f2bf(float f) {
  __hip_bfloat16 h = __float2bfloat16(f);
  return __builtin_bit_cast(unsigned short, h);
}

__device__ __forceinline__ void gload_lds16(const void* g, void* l) {
  __builtin_amdgcn_global_load_lds(
      (const __attribute__((address_space(1))) void*)g,
      (__attribute__((address_space(3))) void*)l, 16, 0, 0);
}

__device__ __forceinline__ void bfly(float2& a, float2& b, float wr, float wi) {
  float tr = wr * b.x - wi * b.y;
  float ti = wr * b.y + wi * b.x;
  b.x = a.x - tr; b.y = a.y - ti;
  a.x += tr; a.y += ti;
}

__device__ __forceinline__ float2 cmul(float2 a, float2 w) {
  return make_float2(a.x * w.x - a.y * w.y, a.x * w.y + a.y * w.x);
}

// 16-point FFT, input bit-reversed in v[], output natural order.
__device__ __forceinline__ void fft16(float2* v) {
  const float C8 = 0.70710678118654752f;
  const float C161 = 0.92387953251128674f, S161 = 0.38268343236508977f;
#pragma unroll
  for (int i = 0; i < 16; i += 2) bfly(v[i], v[i + 1], 1.f, 0.f);
#pragma unroll
  for (int i = 0; i < 16; i += 4) {
    bfly(v[i], v[i + 2], 1.f, 0.f);
    bfly(v[i + 1], v[i + 3], 0.f, -1.f);
  }
  {
    const float w8r[4] = {1.f, C8, 0.f, -C8};
    const float w8i[4] = {0.f, -C8, -1.f, -C8};
#pragma unroll
    for (int i = 0; i < 16; i += 8) {
#pragma unroll
      for (int j = 0; j < 4; ++j) bfly(v[i + j], v[i + j + 4], w8r[j], w8i[j]);
    }
  }
  {
    const float w16r[8] = {1.f, C161, C8, S161, 0.f, -S161, -C8, -C161};
    const float w16i[8] = {0.f, -S161, -C8, -C161, -1.f, -C161, -C8, -S161};
#pragma unroll
    for (int j = 0; j < 8; ++j) bfly(v[j], v[j + 8], w16r[j], w16i[j]);
  }
}

// 8-point FFT, input bit-reversed in v[], output natural order.
__device__ __forceinline__ void fft8(float2* v) {
  const float C8 = 0.70710678118654752f;
#pragma unroll
  for (int i = 0; i < 8; i += 2) bfly(v[i], v[i + 1], 1.f, 0.f);
#pragma unroll
  for (int i = 0; i < 8; i += 4) {
    bfly(v[i], v[i + 2], 1.f, 0.f);
    bfly(v[i + 1], v[i + 3], 0.f, -1.f);
  }
  bfly(v[0], v[4], 1.f, 0.f);
  bfly(v[1], v[5], C8, -C8);
  bfly(v[2], v[6], 0.f, -1.f);
  bfly(v[3], v[7], -C8, -C8);
}

// swizzled index into the [128][64] float2 tile (keeps bit0 -> float4 ok)
__device__ __forceinline__ int TIX(int r, int cc) {
  return (r << 6) + (cc ^ ((r & 7) << 1));
}

// ---------------------------------------------------------------------------
// Kernel 1: REAL-input 128x128 FFT2 + fftshift + amp/phase -> bf16 feats.
// Row pass: 64-pt complex FFT of packed row (z = x[2m] + i x[2m+1]) then
// untangle X(k)=Ze+W*Zo, X(64-k)=conj(Ze-W*Zo); keep only cols 0..64
// (conjugate symmetry). Tile = [128][64] float2 (64KB) + col-64 array (1KB)
// -> 2 blocks/CU. Col pass: 64 column FFTs + 8-thread col-64 tail; mirror
// outputs amp-copy / phase-negate. 512 threads.
// ---------------------------------------------------------------------------
__global__ __launch_bounds__(512, 4) void fft_feats_kernel(
    const float* __restrict__ img, unsigned short* __restrict__ feats) {
  __shared__ float2 tile[128 * 64];
  __shared__ float2 sm64[128];
  __shared__ float2 tw[128];
  const int tid = threadIdx.x;
  const int ch = blockIdx.x, b = blockIdx.y;
  const float* src = img + ((size_t)(b * 3 + ch) << 14);

  static const int BR4[16] = {0, 8, 4, 12, 2, 10, 6, 14, 1, 9, 5, 13, 3, 11, 7, 15};
  static const int BR3[8] = {0, 4, 2, 6, 1, 5, 3, 7};

  if (tid < 128) {
    float sv, cv;
    sincosf(-6.28318530717958647692f * (float)tid / 128.0f, &sv, &cv);
    tw[tid] = make_float2(cv, sv);
  }
  // load: row-major reals reinterpreted as packed complex z(m)=x(2m)+ix(2m+1)
#pragma unroll
  for (int it = 0; it < 8; ++it) {
    int i4 = it * 512 + tid;          // 0..4095
    int r = i4 >> 5, c4 = i4 & 31;
    float4 x = *reinterpret_cast<const float4*>(src + (i4 << 2));
    *reinterpret_cast<float4*>(&tile[TIX(r, c4 * 2)]) = x;
  }
  __syncthreads();

  // ---- row pass stage 1: 64-pt FFT stage (8x8), unit (r, n2)
#pragma unroll
  for (int it = 0; it < 2; ++it) {
    int g = it * 512 + tid;
    int r = g >> 3, n2 = g & 7;
    float2 v[8];
#pragma unroll
    for (int j = 0; j < 8; ++j) v[j] = tile[TIX(r, (BR3[j] << 3) + n2)];
    fft8(v);
#pragma unroll
    for (int k1 = 1; k1 < 8; ++k1) v[k1] = cmul(v[k1], tw[2 * n2 * k1]);
#pragma unroll
    for (int k1 = 0; k1 < 8; ++k1) tile[TIX(r, (k1 << 3) + n2)] = v[k1];
  }
  __syncthreads();

  // ---- row pass stage 2: both halves read, one barrier, then write
  {
    int r0 = tid >> 3, t8 = tid & 7;  // rows 0..63
    int r1 = r0 + 64;
    float2 ua[8], ub[8];
#pragma unroll
    for (int j = 0; j < 8; ++j) {
      ua[j] = tile[TIX(r0, (t8 << 3) + BR3[j])];
      ub[j] = tile[TIX(r1, (t8 << 3) + BR3[j])];
    }
    __syncthreads();  // all reads before any writes
    fft8(ua);
    fft8(ub);
#pragma unroll
    for (int k2 = 0; k2 < 8; ++k2) {
      tile[TIX(r0, t8 + (k2 << 3))] = ua[k2];
      tile[TIX(r1, t8 + (k2 << 3))] = ub[k2];
    }
  }
  __syncthreads();

  // ---- untangle: Z (64-pt of packed) -> X (128-pt of real row), cols 0..64
#pragma unroll
  for (int it = 0; it < 8; ++it) {
    int g = it * 512 + tid;           // 0..4095
    int r = g >> 5, k = g & 31;
    if (k == 0) {
      float2 z0 = tile[TIX(r, 0)];
      float2 z32 = tile[TIX(r, 32)];
      tile[TIX(r, 0)] = make_float2(z0.x + z0.y, 0.f);   // X(0) real
      sm64[r] = make_float2(z0.x - z0.y, 0.f);           // X(64) real
      tile[TIX(r, 32)] = make_float2(z32.x, -z32.y);     // X(32)=conj(Z32)
    } else {
      float2 zk = tile[TIX(r, k)];
      float2 zm = tile[TIX(r, 64 - k)];
      float2 ze = make_float2(0.5f * (zk.x + zm.x), 0.5f * (zk.y - zm.y));
      float2 zo = make_float2(0.5f * (zk.y + zm.y), -0.5f * (zk.x - zm.x));
      float2 t = cmul(zo, tw[k]);
      tile[TIX(r, k)] = make_float2(ze.x + t.x, ze.y + t.y);
      tile[TIX(r, 64 - k)] = make_float2(ze.x - t.x, -(ze.y - t.y));
    }
  }
  __syncthreads();

  // ---- col pass stage 1: 128-pt (16x8) on cols 0..63, unit (col, n2)
  {
    int col = tid & 63, n2 = tid >> 6;
    float2 v[16];
#pragma unroll
    for (int j = 0; j < 16; ++j) v[j] = tile[TIX((BR4[j] << 3) + n2, col)];
    fft16(v);
#pragma unroll
    for (int k1 = 1; k1 < 16; ++k1) v[k1] = cmul(v[k1], tw[n2 * k1]);
#pragma unroll
    for (int k1 = 0; k1 < 16; ++k1) tile[TIX((k1 << 3) + n2, col)] = v[k1];
    if (tid < 8) {  // col-64 tail (real column in sm64)
      int m2 = tid;
      float2 w[16];
#pragma unroll
      for (int j = 0; j < 16; ++j) w[j] = sm64[(BR4[j] << 3) + m2];
      fft16(w);
#pragma unroll
      for (int k1 = 1; k1 < 16; ++k1) w[k1] = cmul(w[k1], tw[m2 * k1]);
#pragma unroll
      for (int k1 = 0; k1 < 16; ++k1) sm64[(k1 << 3) + m2] = w[k1];
    }
  }
  __syncthreads();

  // ---- col pass stage 2 + fftshift + amp/phase (+conjugate mirror writes)
  unsigned short* dst = feats + (size_t)b * IN_DIM + ch * 32768;
  {
    int col = tid & 63, t8 = tid >> 6;
    float2 u0[8], u1[8];
#pragma unroll
    for (int j = 0; j < 8; ++j) {
      u0[j] = tile[TIX((t8 << 3) + BR3[j], col)];
      u1[j] = tile[TIX(((t8 + 8) << 3) + BR3[j], col)];
    }
    fft8(u0);
    fft8(u1);
    const int ow = col + 64;       // col ^ 64 for col<64
    const int owm = 64 - col;      // mirror column (valid col>=1)
#pragma unroll
    for (int k2 = 0; k2 < 8; ++k2) {
#pragma unroll
      for (int half = 0; half < 2; ++half) {
        float2 F = half ? u1[k2] : u0[k2];
        int kh = t8 + half * 8 + (k2 << 4);
        float amp = sqrtf(F.x * F.x + F.y * F.y);
        float ph = atan2f(F.y, F.x);
        int oh = kh ^ 64;
        dst[(oh << 7) + ow] = f2bf(amp);
        dst[16384 + (oh << 7) + ow] = f2bf(ph);
        if (col != 0) {
          int khm = (128 - kh) & 127;
          int ohm = khm ^ 64;
          dst[(ohm << 7) + owm] = f2bf(amp);
          dst[16384 + (ohm << 7) + owm] = f2bf(-ph);
        }
      }
    }
    if (tid < 8) {  // col-64 outputs (ow = 0, self-conjugate, no mirror)
      int t8t = tid;
      float2 e0[8], e1[8];
#pragma unroll
      for (int j = 0; j < 8; ++j) {
        e0[j] = sm64[(t8t << 3) + BR3[j]];
        e1[j] = sm64[((t8t + 8) << 3) + BR3[j]];
      }
      fft8(e0);
      fft8(e1);
#pragma unroll
      for (int k2 = 0; k2 < 8; ++k2) {
#pragma unroll
        for (int half = 0; half < 2; ++half) {
          float2 F = half ? e1[k2] : e0[k2];
          int kh = t8t + half * 8 + (k2 << 4);
          float amp = sqrtf(F.x * F.x + F.y * F.y);
          float ph = atan2f(F.y, F.x);
          int oh = kh ^ 64;
          dst[(oh << 7)] = f2bf(amp);
          dst[16384 + (oh << 7)] = f2bf(ph);
        }
      }
    }
  }
}

// ---------------------------------------------------------------------------
// Kernel 2: layer-1 GEMM (unchanged from R8). MT=256, NT=128, S=64 split-K,
// grid 256 = 1 block/CU, 512 threads. A via global_load_lds depth-4;
// B reg-staged fp32->bf16 once per tile; one s_barrier/iter, counted vmcnt.
// ---------------------------------------------------------------------------
#define GS 64
#define GITERS 48

__global__ __launch_bounds__(512, 2) void gemm1_kernel(
    const unsigned short* __restrict__ feats, const float* __restrict__ W1,
    float* __restrict__ partial) {
  __shared__ __align__(16) unsigned short Asm[4][256 * 32];
  __shared__ __align__(16) unsigned short Bsm[2][128 * 32];
  const int tid = threadIdx.x;
  const int wv = tid >> 6, lane = tid & 63;

  const int f = blockIdx.x;
  const int xcd = f & 7, v = f >> 3;
  const int ks = xcd * 8 + (v & 7);
  const int nt = v >> 3;
  const int n0 = nt * 128;
  const size_t k0 = (size_t)ks * (GITERS * 32);

  const int al_row = lane >> 2;
  const int al_k = (lane & 3) * 8;
  const int brow = tid >> 2, bq = tid & 3;
  const float* bsrc = W1 + (size_t)(n0 + brow) * IN_DIM + k0 + bq * 8;

  auto stageA = [&](int buf, int it) {
    const size_t kb = k0 + (size_t)it * 32;
#pragma unroll
    for (int tl = 0; tl < 2; ++tl) {
      const int s = wv * 2 + tl;
      const unsigned short* ga =
          feats + (size_t)(s * 16 + al_row) * IN_DIM + kb + al_k;
      gload_lds16(ga, (char*)&Asm[buf][0] + s * 1024);
    }
  };

  float4 br0, br1;
  auto loadB = [&](int it) {
    const float* p = bsrc + (size_t)it * 32;
    br0 = *reinterpret_cast<const float4*>(p);
    br1 = *reinterpret_cast<const float4*>(p + 4);
  };
  auto writeB = [&](int buf) {
    u16x8 bw;
    bw[0] = f2bf(br0.x); bw[1] = f2bf(br0.y); bw[2] = f2bf(br0.z); bw[3] = f2bf(br0.w);
    bw[4] = f2bf(br1.x); bw[5] = f2bf(br1.y); bw[6] = f2bf(br1.z); bw[7] = f2bf(br1.w);
    *reinterpret_cast<u16x8*>(&Bsm[buf][brow * 32 + bq * 8]) = bw;
  };

  f32x4 acc[4][4];
#pragma unroll
  for (int i = 0; i < 4; ++i)
#pragma unroll
    for (int jj = 0; jj < 4; ++jj) acc[i][jj] = (f32x4){0.f, 0.f, 0.f, 0.f};

  const int mr = wv & 3;
  const int nc = wv >> 2;
  const int rm = lane & 15, hi = lane >> 4;

  stageA(0, 0);
  stageA(1, 1);
  stageA(2, 2);
  loadB(0);
  asm volatile("s_waitcnt vmcnt(0)" ::: "memory");
  writeB(0);
  loadB(1);

  for (int k = 0; k < GITERS; ++k) {
    const int rem = GITERS - 1 - k;
    if (rem >= 1) {
      asm volatile("s_waitcnt vmcnt(4) lgkmcnt(0)" ::: "memory");
    } else {
      asm volatile("s_waitcnt vmcnt(0) lgkmcnt(0)" ::: "memory");
    }
    __builtin_amdgcn_sched_barrier(0);
    __builtin_amdgcn_s_barrier();
    __builtin_amdgcn_sched_barrier(0);

    const int abuf = k & 3, bbuf = k & 1;
    bh8 afr[4], bfr[4];
#pragma unroll
    for (int i = 0; i < 4; ++i) {
      const int row = mr * 64 + i * 16 + rm;
      afr[i] = *reinterpret_cast<const bh8*>(&Asm[abuf][row * 32 + hi * 8]);
    }
#pragma unroll
    for (int jj = 0; jj < 4; ++jj) {
      const int row = nc * 64 + jj * 16 + rm;
      bfr[jj] = *reinterpret_cast<const bh8*>(&Bsm[bbuf][row * 32 + hi * 8]);
    }
    __builtin_amdgcn_sched_barrier(0);

    if (rem >= 3) stageA((k + 3) & 3, k + 3);

    if (rem >= 1) {
      if (rem >= 3) {
        asm volatile("s_waitcnt vmcnt(2)" ::: "memory");
      } else {
        asm volatile("s_waitcnt vmcnt(0)" ::: "memory");
      }
      __builtin_amdgcn_sched_barrier(0);
      writeB((k + 1) & 1);
      if (rem >= 2) loadB(k + 2);
    }

    asm volatile("s_waitcnt lgkmcnt(1)" ::: "memory");
    __builtin_amdgcn_sched_barrier(0);

#pragma unroll
    for (int i = 0; i < 4; ++i)
#pragma unroll
      for (int jj = 0; jj < 4; ++jj)
        acc[i][jj] = __builtin_amdgcn_mfma_f32_16x16x32_bf16(
            afr[i], bfr[jj], acc[i][jj], 0, 0, 0);
  }

  const int rg = lane >> 4;
  float* pbase = partial + ((size_t)ks << 17);
#pragma unroll
  for (int i = 0; i < 4; ++i) {
#pragma unroll
    for (int jj = 0; jj < 4; ++jj) {
      const int n = n0 + nc * 64 + jj * 16 + rm;
#pragma unroll
      for (int r = 0; r < 4; ++r) {
        const int m = mr * 64 + i * 16 + rg * 4 + r;
        pbase[((size_t)m << 9) + n] = acc[i][jj][r];
      }
    }
  }
}

// ---------------------------------------------------------------------------
// Kernel 3: reduce split-K partials + bias + ReLU -> x1 [256][512] fp32
// ---------------------------------------------------------------------------
__global__ __launch_bounds__(256) void reduce1_kernel(
    const float* __restrict__ partial, const float* __restrict__ b1,
    float* __restrict__ x1, int S) {
  int i = blockIdx.x * 256 + threadIdx.x;
  float s = b1[i & 511];
  for (int p = 0; p < S; ++p) s += partial[((size_t)p << 17) + i];
  x1[i] = fmaxf(s, 0.0f);
}

// ---------------------------------------------------------------------------
// Kernel 4: x2 = relu(x1 @ W2^T + b2)
// ---------------------------------------------------------------------------
__global__ __launch_bounds__(256) void fc2_kernel(
    const float* __restrict__ x1, const float* __restrict__ W2,
    const float* __restrict__ b2, float* __restrict__ x2) {
  __shared__ float xs[512];
  int b = blockIdx.x, n = threadIdx.x;
  xs[n] = x1[b * 512 + n];
  xs[n + 256] = x1[b * 512 + 256 + n];
  __syncthreads();
  float acc = b2[n];
  const float* wr = W2 + (size_t)n * 512;
#pragma unroll 4
  for (int k = 0; k < 512; k += 4) {
    float4 w = *reinterpret_cast<const float4*>(wr + k);
    acc += xs[k] * w.x + xs[k + 1] * w.y + xs[k + 2] * w.z + xs[k + 3] * w.w;
  }
  x2[b * 256 + n] = fmaxf(acc, 0.0f);
}

// ---------------------------------------------------------------------------
// Kernel 5: out = x2 @ W3^T + b3
// ---------------------------------------------------------------------------
__global__ __launch_bounds__(128) void fc3_kernel(
    const float* __restrict__ x2, const float* __restrict__ W3,
    const float* __restrict__ b3, float* __restrict__ out) {
  __shared__ float xs[256];
  int b = blockIdx.x, n = threadIdx.x;
  xs[n] = x2[b * 256 + n];
  xs[n + 128] = x2[b * 256 + 128 + n];
  __syncthreads();
  float acc = b3[n];
  const float* wr = W3 + (size_t)n * 256;
#pragma unroll 4
  for (int k = 0; k < 256; k += 4) {
    float4 w = *reinterpret_cast<const float4*>(wr + k);
    acc += xs[k] * w.x + xs[k + 1] * w.y + xs[k + 2] * w.z + xs[k + 3] * w.w;
  }
  out[b * 128 + n] = acc;
}

extern "C" void kernel_launch(void* const* d_in, const int* in_sizes, int n_in,
                              void* d_out, int out_size, void* d_ws, size_t ws_size,
                              hipStream_t stream) {
  const float* img = (const float*)d_in[0];
  const float* W1 = (const float*)d_in[1];
  const float* b1 = (const float*)d_in[2];
  const float* W2 = (const float*)d_in[3];
  const float* b2 = (const float*)d_in[4];
  const float* W3 = (const float*)d_in[5];
  const float* b3 = (const float*)d_in[6];
  float* out = (float*)d_out;
  char* ws = (char*)d_ws;

  const size_t FEATS_B = 50331648ull;  // bf16 [256][98304]
  unsigned short* feats = (unsigned short*)ws;
  float* partial = (float*)(ws + FEATS_B);
  float* x1 = partial + (size_t)GS * 131072;
  float* x2 = x1 + 131072;

  hipLaunchKernelGGL(fft_feats_kernel, dim3(3, 256), dim3(512), 0, stream, img, feats);
  hipLaunchKernelGGL(gemm1_kernel, dim3(256), dim3(512), 0, stream, feats, W1, partial);
  hipLaunchKernelGGL(reduce1_kernel, dim3(512), dim3(256), 0, stream, partial, b1, x1, GS);
  hipLaunchKernelGGL(fc2_kernel, dim3(256), dim3(256), 0, stream, x1, W2, b2, x2);
  hipLaunchKernelGGL(fc3_kernel, dim3(256), dim3(128), 0, stream, x2, W3, b3, out);
}